// Round 3
// baseline (209.488 us; speedup 1.0000x reference)
//
#include <hip/hip_runtime.h>

#define HW 129600
#define WG 360
#define HG 360
#define NCLS 10
#define NPROP 200
#define CDIM 128
#define NROWS 80000
#define NB 2
#define SEL_CAP 8192
#define HBINS 4096       // heat in (0,1]: (bits>>18) <= 0x3F80>>2 = 4064
#define CHUNK 4096
#define RPB 64           // rows per k_head block
#define FSTRIDE 132      // 128 + 4 pad: 16B-aligned rows, 4-way-max conflicts

// ---------------------------------------------------------------------------
// Shared NMS value: 3x3 local-max suppression, classes 8/9 pass-through,
// border rows/cols suppressed (reference's local_max stays 0 there).
// ---------------------------------------------------------------------------
__device__ __forceinline__ float nms_val(const float* __restrict__ hp, int pos,
                                         int cl) {
  float v = hp[pos];
  if (cl >= 8) return v;
  int y = pos / WG, x = pos - y * WG;
  if (y == 0 || y == HG - 1 || x == 0 || x == WG - 1) return 0.f;
  float m = v;
  m = fmaxf(m, hp[pos - 1]);
  m = fmaxf(m, hp[pos + 1]);
  m = fmaxf(m, hp[pos - WG - 1]);
  m = fmaxf(m, hp[pos - WG]);
  m = fmaxf(m, hp[pos - WG + 1]);
  m = fmaxf(m, hp[pos + WG - 1]);
  m = fmaxf(m, hp[pos + WG]);
  m = fmaxf(m, hp[pos + WG + 1]);
  return (v == m) ? v : 0.f;
}

// ---------------------------------------------------------------------------
// K1: fused MLP head, SGPR-broadcast weights.
// Block = 256 thr = 4 waves; block tile = 64 rows x 128 cols.
// Lane = row (64 rows/wave); wave w covers cols [w*32, w*32+32).
// f staged in LDS (row-major, stride 132); W1/W2/b1 read via wave-uniform
// indices -> s_load + FMA-with-SGPR-operand. Layer-1 k-order is sequential
// 0..127 per output (bit-identical to R2's passing kernel).
// ---------------------------------------------------------------------------
__global__ __launch_bounds__(256) void k_head(
    const float* __restrict__ feat, const float* __restrict__ W1,
    const float* __restrict__ b1, const float* __restrict__ W2,
    const float* __restrict__ b2, const int* __restrict__ idxs,
    float* __restrict__ dense_heat, int* __restrict__ rowmap) {
  __shared__ __align__(16) float lds_f[RPB * FSTRIDE];  // 33792 B; reused for partials
  __shared__ int lds_b[RPB];
  __shared__ int lds_p[RPB];
  const int tid = threadIdx.x;
  const int row0 = blockIdx.x * RPB;

  if (tid < RPB) {
    int row = row0 + tid;
    int bb = idxs[row * 3 + 0];
    int yy = idxs[row * 3 + 1];
    int xx = idxs[row * 3 + 2];
    lds_b[tid] = bb;
    lds_p[tid] = yy * WG + xx;
    rowmap[(size_t)bb * HW + yy * WG + xx] = row;
  }
  // stage f: 64 rows x 128 k (2048 float4), coalesced 1KB/wave-instr
#pragma unroll
  for (int i = 0; i < 8; ++i) {
    int fi = tid + i * 256;
    int r = fi >> 5, k4 = fi & 31;
    float4 v = *(const float4*)(feat + (size_t)(row0 + r) * CDIM + k4 * 4);
    *(float4*)(lds_f + r * FSTRIDE + k4 * 4) = v;
  }
  __syncthreads();

  const int lane = tid & 63;
  const int c0 = __builtin_amdgcn_readfirstlane((tid >> 6) << 5);  // wave-uniform
  float acc[32];
#pragma unroll
  for (int c = 0; c < 32; ++c) acc[c] = 0.f;

  const float* fr = lds_f + lane * FSTRIDE;
  for (int k = 0; k < CDIM; k += 4) {
    float4 f4 = *(const float4*)(fr + k);
#pragma unroll
    for (int h = 0; h < 2; ++h) {
#pragma unroll
      for (int cc = 0; cc < 16; ++cc) {
        const int c = c0 + h * 16 + cc;
        float a = acc[h * 16 + cc];
        a = fmaf(f4.x, W1[(k + 0) * CDIM + c], a);
        a = fmaf(f4.y, W1[(k + 1) * CDIM + c], a);
        a = fmaf(f4.z, W1[(k + 2) * CDIM + c], a);
        a = fmaf(f4.w, W1[(k + 3) * CDIM + c], a);
        acc[h * 16 + cc] = a;
      }
    }
  }

  // layer 2 partials: p[j] = sum_{cc} relu(acc+b1) * W2[c][j]  (W2 uniform)
  float p[NCLS];
#pragma unroll
  for (int j = 0; j < NCLS; ++j) p[j] = 0.f;
#pragma unroll
  for (int cc = 0; cc < 32; ++cc) {
    const int c = c0 + cc;
    float hv = fmaxf(acc[cc] + b1[c], 0.f);
#pragma unroll
    for (int j = 0; j < NCLS; ++j) p[j] = fmaf(hv, W2[c * NCLS + j], p[j]);
  }

  __syncthreads();  // all lds_f reads done; safe to alias
  float* part = lds_f;  // [wave][row*10+j] : 4*640 floats
  {
    const int w = tid >> 6;
#pragma unroll
    for (int j = 0; j < NCLS; ++j) part[w * (RPB * NCLS) + lane * NCLS + j] = p[j];
  }
  __syncthreads();
  for (int o = tid; o < RPB * NCLS; o += 256) {
    int r = o / NCLS, j = o - r * NCLS;
    float s = part[o] + part[640 + o] + part[1280 + o] + part[1920 + o] + b2[j];
    float heat = 1.0f / (1.0f + expf(-s));
    dense_heat[((size_t)lds_b[r] * NCLS + j) * HW + lds_p[r]] = heat;
  }
}

// ---------------------------------------------------------------------------
// K2: NMS + per-block LDS histogram (4096 bins = 16 KB), flush nonzero bins
// with uncontended global atomics.
// ---------------------------------------------------------------------------
__global__ __launch_bounds__(256) void k_nms_hist(
    const float* __restrict__ dense_heat, unsigned int* __restrict__ hist) {
  __shared__ unsigned int lh[HBINS];
  const int cl = blockIdx.y;
  const int b = blockIdx.z;
  const int p0 = blockIdx.x * CHUNK;
  for (int i = threadIdx.x; i < HBINS; i += 256) lh[i] = 0;
  __syncthreads();
  const float* hp = dense_heat + ((size_t)b * NCLS + cl) * HW;
  for (int it = 0; it < CHUNK; it += 256) {
    int pos = p0 + it + threadIdx.x;
    if (pos < HW) {
      float out = nms_val(hp, pos, cl);
      if (out > 0.f) atomicAdd(&lh[__float_as_uint(out) >> 18], 1u);
    }
  }
  __syncthreads();
  unsigned int* gh = hist + (size_t)b * HBINS;
  for (int i = threadIdx.x; i < HBINS; i += 256) {
    unsigned int c = lh[i];
    if (c) atomicAdd(&gh[i], c);
  }
}

// ---------------------------------------------------------------------------
// K3: per-block threshold recompute (cheap, L2-hot hist) + NMS recompute +
// compact survivors (~200-400 total -> few hundred aggregated atomics).
// ---------------------------------------------------------------------------
__global__ __launch_bounds__(256) void k_collect(
    const float* __restrict__ dense_heat, const unsigned int* __restrict__ hist,
    unsigned long long* __restrict__ sel, int* __restrict__ sel_cnt) {
  __shared__ unsigned int coarse[256];
  __shared__ int sT;
  const int cl = blockIdx.y;
  const int b = blockIdx.z;
  const unsigned int* h = hist + (size_t)b * HBINS;
  unsigned int s = 0;
  for (int i = 0; i < 16; ++i) s += h[threadIdx.x * 16 + i];
  coarse[threadIdx.x] = s;
  __syncthreads();
  if (threadIdx.x == 0) {
    unsigned int cum = 0;
    int T = 0;
    int ci = 255;
    for (; ci >= 0; --ci) {
      if (cum + coarse[ci] >= NPROP) break;
      cum += coarse[ci];
    }
    if (ci >= 0) {
      int t = 15;
      for (; t > 0; --t) {
        unsigned int c = h[ci * 16 + t];
        if (cum + c >= NPROP) break;
        cum += c;
      }
      T = ci * 16 + t;
    }
    sT = T;
  }
  __syncthreads();
  const int T = sT;
  const float* hp = dense_heat + ((size_t)b * NCLS + cl) * HW;
  const int p0 = blockIdx.x * CHUNK;
  for (int it = 0; it < CHUNK; it += 256) {
    int pos = p0 + it + threadIdx.x;
    float out = 0.f;
    if (pos < HW) out = nms_val(hp, pos, cl);
    unsigned int bits = __float_as_uint(out);
    bool pred = (out > 0.f) && ((int)(bits >> 18) >= T);
    unsigned long long mask = __ballot(pred);
    if (pred) {
      int lane = threadIdx.x & 63;
      int lb = __popcll(mask & ((1ull << lane) - 1ull));
      int base = 0;
      if (lb == 0) base = atomicAdd(&sel_cnt[b], (int)__popcll(mask));
      base = __builtin_amdgcn_readfirstlane(base);
      unsigned int gidx = (unsigned int)cl * HW + (unsigned int)pos;
      // key: heat bits desc, then smaller gidx first (jax top_k tie-break)
      unsigned long long key =
          ((unsigned long long)bits << 32) | (unsigned long long)(~gidx);
      int slot = base + lb;
      if (slot < SEL_CAP) sel[(size_t)b * SEL_CAP + slot] = key;
    }
  }
}

// ---------------------------------------------------------------------------
// K4: exact top-200 by rank-counting (keys unique -> ranks distinct), then
// cooperative coalesced emit of qf / query_pos / qhs / cls.
// ---------------------------------------------------------------------------
__global__ __launch_bounds__(256) void k_final(
    const unsigned long long* __restrict__ sel, const int* __restrict__ sel_cnt,
    const float* __restrict__ dense_heat, const int* __restrict__ rowmap,
    const float* __restrict__ feat, const float* __restrict__ Wc,
    const float* __restrict__ bc, float* __restrict__ out) {
  __shared__ unsigned long long sk[SEL_CAP];
  __shared__ unsigned long long winners[NPROP];
  __shared__ int wpos[NPROP];
  __shared__ int wcls[NPROP];
  __shared__ int wrow[NPROP];
  const int b = blockIdx.x;
  const int tid = threadIdx.x;
  int M = sel_cnt[b];
  if (M > SEL_CAP) M = SEL_CAP;
  for (int i = tid; i < M; i += 256) sk[i] = sel[(size_t)b * SEL_CAP + i];
  __syncthreads();
  for (int i = tid; i < M; i += 256) {
    unsigned long long key = sk[i];
    int rank = 0;
    for (int j = 0; j < M; ++j) rank += (sk[j] > key) ? 1 : 0;
    if (rank < NPROP) winners[rank] = key;
  }
  __syncthreads();
  if (tid < NPROP) {
    unsigned long long key = winners[tid];
    unsigned int gidx = ~((unsigned int)(key & 0xFFFFFFFFull));
    int cls = (int)(gidx / HW);
    int pos = (int)(gidx - (unsigned int)cls * HW);
    int y = pos / WG, x = pos - y * WG;
    wpos[tid] = pos;
    wcls[tid] = cls;
    wrow[tid] = rowmap[(size_t)b * HW + pos];
    out[51200 + ((size_t)b * NPROP + tid) * 2 + 0] = (float)x;
    out[51200 + ((size_t)b * NPROP + tid) * 2 + 1] = (float)y;
    out[56000 + b * NPROP + tid] = (float)cls;
  }
  __syncthreads();
  // qhs (B, NCLS, NPROP) at 52000
  for (int o = tid; o < NCLS * NPROP; o += 256) {
    int j = o / NPROP, pp = o - j * NPROP;
    const float* hp = dense_heat + ((size_t)b * NCLS + j) * HW;
    out[52000 + (size_t)b * NCLS * NPROP + o] = nms_val(hp, wpos[pp], j);
  }
  // qf (B, C, NPROP) at 0
  for (int o = tid; o < CDIM * NPROP; o += 256) {
    int c = o / NPROP, pp = o - c * NPROP;
    out[(size_t)b * CDIM * NPROP + o] =
        feat[(size_t)wrow[pp] * CDIM + c] + Wc[c * NCLS + wcls[pp]] + bc[c];
  }
}

// ---------------------------------------------------------------------------
// ws layout (bytes):
//   [0)          dense_heat : B*10*HW*4 = 10,368,000
//   [10368000)   hist       : B*4096*4  =     32,768
//   [10400768)   rowmap     : B*HW*4    =  1,036,800
//   [11437568)   sel        : B*8192*8  =    131,072
//   [11568640)   cnts       : sel_cnt[2]
// ---------------------------------------------------------------------------
extern "C" void kernel_launch(void* const* d_in, const int* in_sizes, int n_in,
                              void* d_out, int out_size, void* d_ws,
                              size_t ws_size, hipStream_t stream) {
  const float* feat = (const float*)d_in[0];
  const float* W1 = (const float*)d_in[1];
  const float* b1 = (const float*)d_in[2];
  const float* W2 = (const float*)d_in[3];
  const float* b2 = (const float*)d_in[4];
  const float* Wc = (const float*)d_in[5];
  const float* bc = (const float*)d_in[6];
  const int* idxs = (const int*)d_in[7];
  float* out = (float*)d_out;

  char* ws = (char*)d_ws;
  float* dense_heat = (float*)(ws + 0);
  unsigned int* hist = (unsigned int*)(ws + 10368000);
  int* rowmap = (int*)(ws + 10400768);
  unsigned long long* sel = (unsigned long long*)(ws + 11437568);
  int* sel_cnt = (int*)(ws + 11568640);

  hipMemsetAsync(dense_heat, 0, (size_t)NB * NCLS * HW * sizeof(float), stream);
  hipMemsetAsync(hist, 0, (size_t)NB * HBINS * sizeof(unsigned int), stream);
  hipMemsetAsync(sel_cnt, 0, 2 * sizeof(int), stream);

  k_head<<<NROWS / RPB, 256, 0, stream>>>(feat, W1, b1, W2, b2, idxs, dense_heat,
                                          rowmap);
  k_nms_hist<<<dim3((HW + CHUNK - 1) / CHUNK, NCLS, NB), 256, 0, stream>>>(
      dense_heat, hist);
  k_collect<<<dim3((HW + CHUNK - 1) / CHUNK, NCLS, NB), 256, 0, stream>>>(
      dense_heat, hist, sel, sel_cnt);
  k_final<<<NB, 256, 0, stream>>>(sel, sel_cnt, dense_heat, rowmap, feat, Wc, bc,
                                  out);
}